// Round 1
// baseline (240.378 us; speedup 1.0000x reference)
//
#include <hip/hip_runtime.h>
#include <hip/hip_bf16.h>

// Problem: B=4, N=2048, IN=256, H=8, ATN=32
//   xt = x@W + b            [B,H,N,32]
//   xC = xt @ C^T           [B,H,N,32]   (contract 2nd index of C)
//   S  = xC @ xt^T          [B,H,N,N]
//   alpha = tanh(S * adj)   [B,H,N,N]    (never materialized)
//   heads = alpha @ xt      [B,H,N,32] -> out [B,N,256] fp32

typedef __bf16 bf16;
typedef __attribute__((ext_vector_type(8))) __bf16 bf16x8;
typedef __attribute__((ext_vector_type(4))) __bf16 bf16x4;
typedef __attribute__((ext_vector_type(4))) float  f32x4;

#define MFMA(a, b, c) __builtin_amdgcn_mfma_f32_16x16x32_bf16(a, b, c, 0, 0, 0)

// Padé tanh: x(945 + 105 t + t^2)/(945 + 420 t + 15 t^2), t = x^2, clamped to [-1,1].
// Max abs err ~1.1e-3 (at |x|~3.6); only one transcendental (v_rcp_f32).
__device__ __forceinline__ float fast_tanh(float x) {
    float t   = x * x;
    float num = x * __builtin_fmaf(t, t + 105.0f, 945.0f);
    float den = __builtin_fmaf(t, __builtin_fmaf(t, 15.0f, 420.0f), 945.0f);
    float r   = num * __builtin_amdgcn_rcpf(den);
    return __builtin_fminf(1.0f, __builtin_fmaxf(-1.0f, r));
}

// ---------------- constants ----------------
#define BB   4
#define NN   2048
#define IND  256
#define HH   8
#define ATN  32

// workspace layout (bytes)
#define OFF_XBF  0u            // x as bf16: B*N*IN         = 2,097,152 elems (4 MB)
#define OFF_XT   4194304u      // xt  [B][H][N][32] bf16    = 2,097,152 (4 MB)
#define OFF_XC   8388608u      // xC  [B][H][N][32] bf16
#define OFF_XTT  12582912u     // xt^T[B][H][32][N] bf16
#define OFF_WT   16777216u     // W^T [H][32][256]  bf16    = 65,536 (128 KB)
#define OFF_CB   16908288u     // C   [H][32][32]   bf16    = 8,192  (16 KB)

// ---------------- kernel 0: dtype conversion ----------------
// part1: x fp32 -> bf16 (float4 per thread): 524288 threads
// part2: W [H][IN][ATN] -> WT [H][ATN][IN] bf16: 65536 threads
// part3: C -> bf16 straight: 8192 threads
__global__ __launch_bounds__(256) void k_prep(const float* __restrict__ x,
                                              const float* __restrict__ W,
                                              const float* __restrict__ C,
                                              bf16* __restrict__ xbf,
                                              bf16* __restrict__ WT,
                                              bf16* __restrict__ Cb) {
    int tid = blockIdx.x * 256 + threadIdx.x;
    if (tid < 524288) {
        float4 v = ((const float4*)x)[tid];
        bf16x4 o;
        o[0] = (bf16)v.x; o[1] = (bf16)v.y; o[2] = (bf16)v.z; o[3] = (bf16)v.w;
        *(bf16x4*)(xbf + (size_t)tid * 4) = o;
    } else if (tid < 524288 + 65536) {
        int t = tid - 524288;
        int h = t >> 13, r = t & 8191, i = r >> 5, o = r & 31;
        WT[(h * 32 + o) * 256 + i] = (bf16)W[t];
    } else if (tid < 524288 + 65536 + 8192) {
        int t = tid - (524288 + 65536);
        Cb[t] = (bf16)C[t];
    }
}

// ---------------- kernel A: projection ----------------
// grid 2048 = b(4) * h(8) * ntile(64); 1 wave/block; 32 rows of n per block.
// xt[32n x 32o] = x[32n x 256] @ W[h][256 x 32] + bias, then xC = xt @ C^T.
__global__ __launch_bounds__(64) void k_proj(const bf16* __restrict__ xbf,
                                             const bf16* __restrict__ WT,
                                             const bf16* __restrict__ Cb,
                                             const float* __restrict__ bias,
                                             bf16* __restrict__ xt,
                                             bf16* __restrict__ xc,
                                             bf16* __restrict__ xtT) {
    __shared__ bf16 lds[32 * 40];   // xt tile, row stride 40 elems (80 B, 16B-aligned)
    int bid = blockIdx.x;
    int nt = bid & 63, h = (bid >> 6) & 7, b = bid >> 9;
    int n0 = nt * 32;
    int lane = threadIdx.x;
    int c = lane & 15, q = lane >> 4;

    f32x4 acc[2][2] = {};
    const bf16* xrow0 = xbf + ((size_t)(b * NN + n0 + c) * IND + q * 8);
    const bf16* xrow1 = xbf + ((size_t)(b * NN + n0 + 16 + c) * IND + q * 8);
    const bf16* wrow0 = WT + ((h * 32 + c) * IND + q * 8);
    const bf16* wrow1 = WT + ((h * 32 + 16 + c) * IND + q * 8);
#pragma unroll
    for (int k0 = 0; k0 < IND; k0 += 32) {
        bf16x8 a0 = *(const bf16x8*)(xrow0 + k0);
        bf16x8 a1 = *(const bf16x8*)(xrow1 + k0);
        bf16x8 w0 = *(const bf16x8*)(wrow0 + k0);
        bf16x8 w1 = *(const bf16x8*)(wrow1 + k0);
        acc[0][0] = MFMA(a0, w0, acc[0][0]);
        acc[0][1] = MFMA(a0, w1, acc[0][1]);
        acc[1][0] = MFMA(a1, w0, acc[1][0]);
        acc[1][1] = MFMA(a1, w1, acc[1][1]);
    }
    float bv[2] = { bias[h * 32 + c], bias[h * 32 + 16 + c] };
    size_t bh = (size_t)(b * HH + h);
    // C/D layout: row(n_local) = q*4+r (+16*nq), col(o_local) = c (+16*oq)
#pragma unroll
    for (int nq = 0; nq < 2; ++nq)
#pragma unroll
        for (int oq = 0; oq < 2; ++oq)
#pragma unroll
            for (int r = 0; r < 4; ++r) {
                float v = acc[nq][oq][r] + bv[oq];
                int n = nq * 16 + q * 4 + r;
                int o = oq * 16 + c;
                bf16 e = (bf16)v;
                xt[(bh * NN + n0 + n) * ATN + o] = e;
                xtT[(bh * ATN + o) * NN + n0 + n] = e;
                lds[n * 40 + o] = e;
            }
    // xC = xt @ C^T : A = xt rows (from LDS), B[k=o][col=p] = C[p][o] (row-major C!)
    f32x4 acc2[2][2] = {};
    bf16x8 aL0 = *(const bf16x8*)(lds + (c) * 40 + q * 8);
    bf16x8 aL1 = *(const bf16x8*)(lds + (16 + c) * 40 + q * 8);
    bf16x8 c0 = *(const bf16x8*)(Cb + h * 1024 + (c) * 32 + q * 8);
    bf16x8 c1 = *(const bf16x8*)(Cb + h * 1024 + (16 + c) * 32 + q * 8);
    acc2[0][0] = MFMA(aL0, c0, acc2[0][0]);
    acc2[0][1] = MFMA(aL0, c1, acc2[0][1]);
    acc2[1][0] = MFMA(aL1, c0, acc2[1][0]);
    acc2[1][1] = MFMA(aL1, c1, acc2[1][1]);
#pragma unroll
    for (int nq = 0; nq < 2; ++nq)
#pragma unroll
        for (int pq = 0; pq < 2; ++pq)
#pragma unroll
            for (int r = 0; r < 4; ++r) {
                int n = nq * 16 + q * 4 + r;
                int p = pq * 16 + c;
                xc[(bh * NN + n0 + n) * ATN + p] = (bf16)acc2[nq][pq][r];
            }
}

// ---------------- kernel B: fused scores/tanh/PV ----------------
// grid 256 = b(4) * ntile(64); 512 threads = 8 waves; wave == head.
// Per m-step(32): S'[m][n] = xt_m @ xC^T (transposed so adj-multiply gets
// contiguous float4 loads), alpha=tanh(S*adj) -> bf16 -> per-wave LDS,
// then O += alpha @ xt via xtT B-frags. adj tile shared by all 8 heads (L2).
__global__ __launch_bounds__(512) void k_attn(const float* __restrict__ adj,
                                              const bf16* __restrict__ xt,
                                              const bf16* __restrict__ xc,
                                              const bf16* __restrict__ xtT,
                                              float* __restrict__ out) {
    __shared__ ushort alds[HH * 32 * 40];   // per-wave alpha tile, 80 B row stride
    int bid = blockIdx.x;
    int nt = bid & 63, b = bid >> 6;
    int n0 = nt * 32;
    int wave = threadIdx.x >> 6;            // == head
    int lane = threadIdx.x & 63;
    int c = lane & 15, q = lane >> 4;
    size_t bh = (size_t)(b * HH + wave);
    const bf16* xt_h = xt + bh * NN * ATN;
    const bf16* xc_h = xc + bh * NN * ATN;
    const bf16* xtT_h = xtT + bh * ATN * NN;
    const float* adj_b = adj + (size_t)b * NN * NN;
    bf16* al = (bf16*)(alds + wave * 32 * 40);

    // scores B-operand: B[k=p][col=n] = xC[n][p], n fixed per block -> preload
    bf16x8 bXC0 = *(const bf16x8*)(xc_h + (n0 + c) * ATN + q * 8);
    bf16x8 bXC1 = *(const bf16x8*)(xc_h + (n0 + 16 + c) * ATN + q * 8);
    f32x4 accO[2][2] = {};
    const f32x4 z = {0.f, 0.f, 0.f, 0.f};

    for (int m0 = 0; m0 < NN; m0 += 32) {
        // scores A-operand: xt rows m
        bf16x8 aXT0 = *(const bf16x8*)(xt_h + (m0 + c) * ATN + q * 8);
        bf16x8 aXT1 = *(const bf16x8*)(xt_h + (m0 + 16 + c) * ATN + q * 8);
        f32x4 S[2][2];
        S[0][0] = MFMA(aXT0, bXC0, z);
        S[0][1] = MFMA(aXT0, bXC1, z);
        S[1][0] = MFMA(aXT1, bXC0, z);
        S[1][1] = MFMA(aXT1, bXC1, z);
        // D layout of S': row = m_local = q*4+r (+16mq), col = n_local = c (+16nq)
        // adj[n][m]: per (mq,nq) lane reads 4 consecutive m -> float4
#pragma unroll
        for (int mq = 0; mq < 2; ++mq)
#pragma unroll
            for (int nq = 0; nq < 2; ++nq) {
                f32x4 av = *(const f32x4*)(adj_b +
                    (size_t)(n0 + nq * 16 + c) * NN + m0 + mq * 16 + q * 4);
                bf16x4 pk;
#pragma unroll
                for (int r = 0; r < 4; ++r)
                    pk[r] = (bf16)fast_tanh(S[mq][nq][r] * av[r]);
                // alpha LDS tile [n_local][m_local], stride 40 elems
                *(bf16x4*)(al + (nq * 16 + c) * 40 + mq * 16 + q * 4) = pk;
            }
        // PV: A[n][k=m] from LDS, B[k=m][col=o] = xtT[o][m]
        bf16x8 aAL0 = *(const bf16x8*)(al + (c) * 40 + q * 8);
        bf16x8 aAL1 = *(const bf16x8*)(al + (16 + c) * 40 + q * 8);
        bf16x8 bXT0 = *(const bf16x8*)(xtT_h + (c) * NN + m0 + q * 8);
        bf16x8 bXT1 = *(const bf16x8*)(xtT_h + (16 + c) * NN + m0 + q * 8);
        accO[0][0] = MFMA(aAL0, bXT0, accO[0][0]);
        accO[0][1] = MFMA(aAL0, bXT1, accO[0][1]);
        accO[1][0] = MFMA(aAL1, bXT0, accO[1][0]);
        accO[1][1] = MFMA(aAL1, bXT1, accO[1][1]);
        __syncthreads();   // pace the 8 head-waves over the shared adj tile (L2 locality)
    }
    // epilogue: O C/D layout: row n_local = q*4+r (+16nq), col o_local = c (+16oq)
#pragma unroll
    for (int nq = 0; nq < 2; ++nq)
#pragma unroll
        for (int oq = 0; oq < 2; ++oq)
#pragma unroll
            for (int r = 0; r < 4; ++r) {
                int n = n0 + nq * 16 + q * 4 + r;
                int o = wave * 32 + oq * 16 + c;
                out[((size_t)b * NN + n) * (HH * ATN) + o] = accO[nq][oq][r];
            }
}

extern "C" void kernel_launch(void* const* d_in, const int* in_sizes, int n_in,
                              void* d_out, int out_size, void* d_ws, size_t ws_size,
                              hipStream_t stream) {
    const float* x    = (const float*)d_in[0];   // [4,2048,256]
    const float* adj  = (const float*)d_in[1];   // [4,2048,2048]
    const float* W    = (const float*)d_in[2];   // [8,256,32]
    const float* bias = (const float*)d_in[3];   // [8,32]
    const float* C    = (const float*)d_in[4];   // [8,32,32]
    float* out = (float*)d_out;                  // [4,2048,256]

    char* ws = (char*)d_ws;                      // needs ~16.2 MB
    bf16* xbf = (bf16*)(ws + OFF_XBF);
    bf16* xt  = (bf16*)(ws + OFF_XT);
    bf16* xc  = (bf16*)(ws + OFF_XC);
    bf16* xtT = (bf16*)(ws + OFF_XTT);
    bf16* WT  = (bf16*)(ws + OFF_WT);
    bf16* Cb  = (bf16*)(ws + OFF_CB);

    k_prep<<<2336, 256, 0, stream>>>(x, W, C, xbf, WT, Cb);
    k_proj<<<2048, 64, 0, stream>>>(xbf, WT, Cb, bias, xt, xc, xtT);
    k_attn<<<256, 512, 0, stream>>>(adj, xt, xc, xtT, out);
}